// Round 9
// baseline (704.806 us; speedup 1.0000x reference)
//
#include <hip/hip_runtime.h>
#include <hip/hip_bf16.h>
#include <stdint.h>

// Problem constants
#define B_  2
#define S_  2048
#define E_  1024
#define H_  16
#define D_  64
#define NE_ 8
#define M_  4096   // B*S

typedef unsigned short u16;
typedef _Float16 f16x8 __attribute__((ext_vector_type(8)));
typedef float f32x4 __attribute__((ext_vector_type(4)));

__device__ __forceinline__ f32x4 fzero4() { f32x4 v; v[0]=0.f; v[1]=0.f; v[2]=0.f; v[3]=0.f; return v; }

__device__ __forceinline__ u16 hbits(_Float16 h) { union { _Float16 f; u16 u; } c; c.f = h; return c.u; }
__device__ __forceinline__ u16 f2h(float v) { return hbits((_Float16)v); }

// ---- fp16 3-term split storage helpers ----
// A-side planes: [Ah, Ah/64, Al*64]   W-side planes: [Wh, Wl*64, Wh/64]
// sum over stacked K' gives Ah*Wh + Ah*Wl + Al*Wh  (lo*lo dropped, ~2^-22 rel)
__device__ __forceinline__ void storeA3(u16* p, size_t stride, float v) {
  _Float16 h = (_Float16)v; float hf = (float)h;
  p[0]        = hbits(h);
  p[stride]   = f2h(hf * 0.015625f);
  p[2*stride] = f2h((v - hf) * 64.0f);
}
__device__ __forceinline__ void storeW3(u16* p, size_t stride, float v) {
  _Float16 h = (_Float16)v; float hf = (float)h;
  p[0]        = hbits(h);
  p[stride]   = f2h((v - hf) * 64.0f);
  p[2*stride] = f2h(hf * 0.015625f);
}
// attention-side 2-plane split: [Xh, Xl*64] (kernel composes terms itself)
__device__ __forceinline__ void store2s(u16* p, size_t stride, float v) {
  _Float16 h = (_Float16)v; float hf = (float)h;
  p[0]      = hbits(h);
  p[stride] = f2h((v - hf) * 64.0f);
}

__device__ __forceinline__ void gload_lds16(const void* g, void* l) {
  __builtin_amdgcn_global_load_lds(
      (const __attribute__((address_space(1))) void*)g,
      (__attribute__((address_space(3))) void*)l, 16, 0, 0);
}

#define MFMA16(a, b, c) __builtin_amdgcn_mfma_f32_16x16x32_f16((a), (b), (c), 0, 0, 0)

// ================= weight conversion =================
__global__ __launch_bounds__(256) void k_splitW(const float* __restrict__ in, u16* __restrict__ out, int total) {
  int idx = blockIdx.x * 256 + threadIdx.x;
  if (idx >= total) return;
  int n = idx >> 10, k = idx & 1023;          // K = 1024
  storeW3(out + (size_t)n * 3072 + k, 1024, in[idx]);
}

__global__ __launch_bounds__(256) void k_convH(const float* __restrict__ in, u16* __restrict__ out, int total) {
  int idx = blockIdx.x * 256 + threadIdx.x;
  if (idx < total) out[idx] = f2h(in[idx]);
}

// ================= RoPE + A-side splits =================
__global__ __launch_bounds__(256) void k_rope3(const float* __restrict__ x, u16* __restrict__ ropeA, u16* __restrict__ xA) {
  int p = blockIdx.x * 256 + threadIdx.x;     // B*S*H*32 = 2097152 pairs
  if (p >= B_ * S_ * H_ * 32) return;
  int i   = p & 31;
  int h   = (p >> 5) & 15;
  int row = p >> 9;                            // b*S + s
  int s   = row & (S_ - 1);
  int col = h * 64 + 2 * i;
  size_t base = (size_t)row * E_ + col;
  float x1 = x[base], x2 = x[base + 1];
  float inv = exp2f(-(float)i * 0.41524101186092029f);  // 10000^(-i/32)
  float ang = (float)s * inv;
  float sn, cs; sincosf(ang, &sn, &cs);
  float r1 = x1 * cs - x2 * sn;
  float r2 = x1 * sn + x2 * cs;
  size_t ob = (size_t)row * 3072 + col;
  storeA3(ropeA + ob,     1024, r1);
  storeA3(ropeA + ob + 1, 1024, r2);
  storeA3(xA + ob,        1024, x1);
  storeA3(xA + ob + 1,    1024, x2);
}

// ================= fused QKV GEMM =================
// grid (24, 32): nt 0..15 -> Q/K from rope3; nt 16..23 -> V from x3.
// C = A(4096x3072) * W(row nt*128..)^T + bias, split-fp16 3-term.
__global__ __launch_bounds__(256) void gemm_qkv(
    const u16* __restrict__ ropeA, const u16* __restrict__ xA,
    const u16* __restrict__ Wall, const float* __restrict__ ipb,
    u16* __restrict__ q2, u16* __restrict__ k2, u16* __restrict__ vt2)
{
  __shared__ __align__(16) u16 lA[128 * 32];
  __shared__ __align__(16) u16 lB[128 * 32];
  const int tid  = threadIdx.x;
  const int lane = tid & 63;
  const int wid  = tid >> 6;
  const int nt = blockIdx.x, mt = blockIdx.y;
  const u16* A = (nt < 16) ? ropeA : xA;
  long aoff[2], boff[2];
#pragma unroll
  for (int i = 0; i < 2; ++i) {
    aoff[i] = (long)(mt * 128 + i * 64 + (tid >> 2)) * 3072 + (tid & 3) * 8;
    boff[i] = (long)(nt * 128 + i * 64 + (tid >> 2)) * 3072 + (tid & 3) * 8;
  }
  f32x4 acc[4][4];
#pragma unroll
  for (int a = 0; a < 4; ++a)
#pragma unroll
    for (int b = 0; b < 4; ++b) acc[a][b] = fzero4();
  const int wm = wid >> 1, wn = wid & 1;
  const int r16 = lane & 15, g4 = lane >> 4;

  for (int k0 = 0; k0 < 3072; k0 += 32) {
#pragma unroll
    for (int i = 0; i < 2; ++i) {
      gload_lds16(A    + aoff[i] + k0, (char*)lA + i * 4096 + wid * 1024);
      gload_lds16(Wall + boff[i] + k0, (char*)lB + i * 4096 + wid * 1024);
    }
    __syncthreads();
    f16x8 af[4], bf[4];
#pragma unroll
    for (int f = 0; f < 4; ++f) {
      af[f] = *(const f16x8*)&lA[(wm * 64 + f * 16 + r16) * 32 + 8 * g4];
      bf[f] = *(const f16x8*)&lB[(wn * 64 + f * 16 + r16) * 32 + 8 * g4];
    }
#pragma unroll
    for (int fm = 0; fm < 4; ++fm)
#pragma unroll
      for (int fn = 0; fn < 4; ++fn)
        acc[fm][fn] = MFMA16(af[fm], bf[fn], acc[fm][fn]);
    __syncthreads();
  }

  const int m0 = mt * 128 + wm * 64;
  const int n0 = nt * 128 + wn * 64;
  const size_t PLV = (size_t)B_ * H_ * 64 * S_;
#pragma unroll
  for (int fm = 0; fm < 4; ++fm) {
#pragma unroll
    for (int fn = 0; fn < 4; ++fn) {
      const int colg = n0 + fn * 16 + r16;
      const float bv = ipb[colg];
#pragma unroll
      for (int i = 0; i < 4; ++i) {
        const int rowg = m0 + fm * 16 + 4 * g4 + i;
        float v = acc[fm][fn][i] + bv;
        int bb = rowg >> 11, s = rowg & 2047;
        if (nt < 16) {
          int col = colg & 1023, hh = col >> 6, d = col & 63;
          u16* tgt = (colg < 1024) ? q2 : k2;
          store2s(tgt + (((size_t)(bb * H_ + hh)) * S_ + s) * 128 + d, 64, v);
        } else {
          int col = colg - 2048, hh = col >> 6, d = col & 63;
          store2s(vt2 + (((size_t)(bb * H_ + hh)) * 64 + d) * (size_t)S_ + s, PLV, v);
        }
      }
    }
  }
}

// ================= generic GEMM (out-proj / MoE), BN-tiled =================
// EPI 2: fp32 plain write   EPI 3: MoE pair write (gathered rows)
template <int EPI, bool GATHER, int BN>
__global__ __launch_bounds__(256) void gemm_bt(
    const u16* __restrict__ A, const u16* __restrict__ Bw,
    const float* __restrict__ bias, void* __restrict__ Cout,
    int M, int N, int K,
    const int* __restrict__ lists, const int* __restrict__ cnt,
    const float* __restrict__ topw)
{
  constexpr int BCH = BN / 64;       // B-staging gloads per lane
  constexpr int FN  = BN / 32;       // N-fragments per wave
  __shared__ __align__(16) u16 lA[128 * 32];
  __shared__ __align__(16) u16 lB[BN * 32];
  const int tid  = threadIdx.x;
  const int lane = tid & 63;
  const int wid  = tid >> 6;
  const int nt = blockIdx.x, mt = blockIdx.y;
  int cnt_e = 0;
  const int* listE = nullptr;
  if constexpr (GATHER) {
    int e = blockIdx.z;
    cnt_e = cnt[e];
    if (mt * 128 >= cnt_e) return;
    Bw   += (size_t)e * N * K;
    bias += (size_t)e * N;
    listE = lists + e * 4096;
  }
  long aoff[2], boff[BCH];
#pragma unroll
  for (int i = 0; i < 2; ++i) {
    long arow;
    if constexpr (GATHER) {
      int li = mt * 128 + i * 64 + (tid >> 2);
      int entry = (li < cnt_e) ? listE[li] : 0;
      arow = entry >> 1;
    } else {
      arow = mt * 128 + i * 64 + (tid >> 2);
    }
    aoff[i] = arow * (long)K + (tid & 3) * 8;
  }
#pragma unroll
  for (int i = 0; i < BCH; ++i)
    boff[i] = (long)(nt * BN + i * 64 + (tid >> 2)) * K + (tid & 3) * 8;

  f32x4 acc[4][FN];
#pragma unroll
  for (int a = 0; a < 4; ++a)
#pragma unroll
    for (int b = 0; b < FN; ++b) acc[a][b] = fzero4();
  const int wm = wid >> 1, wn = wid & 1;
  const int r16 = lane & 15, g4 = lane >> 4;

  for (int k0 = 0; k0 < K; k0 += 32) {
#pragma unroll
    for (int i = 0; i < 2; ++i)
      gload_lds16(A + aoff[i] + k0, (char*)lA + i * 4096 + wid * 1024);
#pragma unroll
    for (int i = 0; i < BCH; ++i)
      gload_lds16(Bw + boff[i] + k0, (char*)lB + i * 4096 + wid * 1024);
    __syncthreads();
    f16x8 af[4], bf[FN];
#pragma unroll
    for (int f = 0; f < 4; ++f)
      af[f] = *(const f16x8*)&lA[(wm * 64 + f * 16 + r16) * 32 + 8 * g4];
#pragma unroll
    for (int f = 0; f < FN; ++f)
      bf[f] = *(const f16x8*)&lB[(wn * (FN * 16) + f * 16 + r16) * 32 + 8 * g4];
#pragma unroll
    for (int fm = 0; fm < 4; ++fm)
#pragma unroll
      for (int fn = 0; fn < FN; ++fn)
        acc[fm][fn] = MFMA16(af[fm], bf[fn], acc[fm][fn]);
    __syncthreads();
  }

  const int m0 = mt * 128 + wm * 64;
  const int n0 = nt * BN + wn * (FN * 16);
#pragma unroll
  for (int fm = 0; fm < 4; ++fm) {
#pragma unroll
    for (int fn = 0; fn < FN; ++fn) {
      const int colg = n0 + fn * 16 + r16;
      const float bv = bias[colg];
#pragma unroll
      for (int i = 0; i < 4; ++i) {
        const int rowg = m0 + fm * 16 + 4 * g4 + i;
        float v = acc[fm][fn][i] + bv;
        if constexpr (EPI == 2) {
          ((float*)Cout)[(size_t)rowg * N + colg] = v;
        } else {
          if (rowg < cnt_e) {
            int entry = listE[rowg];
            ((float*)Cout)[(size_t)entry * 1024 + colg] = v * topw[entry];
          }
        }
      }
    }
  }
}

// ================= flash attention v5: 4 waves/block, QBLK=128, KVBLK=64 =================
// Each wave owns 32 q-rows (two 16-row groups). K-fragments read once from LDS
// feed both groups (halves K LDS traffic per unit work); steps/barriers halve.
// Pl reused sequentially per group. All swizzle/numeric algebra as verified.
__global__ __launch_bounds__(256) void k_attn8(const u16* __restrict__ Q2, const u16* __restrict__ K2,
                                               const u16* __restrict__ VT2, u16* __restrict__ ctx3) {
  __shared__ __align__(16) u16 Kl[2][64 * 128];       // 32 KB  [buf][key][hi64|lo64]
  __shared__ __align__(16) u16 Vl[2][2 * 64 * 64];    // 32 KB  [buf][plane][d][k]
  __shared__ __align__(16) u16 Pl[4][2 * 1024];       // 16 KB  [wave][plane][16 x 64]
  const int tid  = threadIdx.x;
  const int w    = tid >> 6;
  const int lane = tid & 63;
  const int r16 = lane & 15, g4 = lane >> 4;

  // Balanced XCD decode for 512 blocks: CU x pairs slots {x, x+32} with
  // complementary qb -> every CU totals 34 K-steps.
  const int bid  = blockIdx.x;
  const int xcd  = bid & 7;
  const int slot = bid >> 3;          // [0,64)
  const int rnd  = slot >> 4;         // [0,4)
  const int c    = slot & 15;
  const int bh   = xcd + 8 * rnd;
  const int qb   = (rnd == 0 || rnd == 3) ? (15 - c) : c;   // [0,16)
  const int nkt  = 2 * qb + 2;        // 64-key steps

  const size_t PLV = (size_t)B_ * H_ * 64 * S_;
  const u16* Qp = Q2  + (size_t)bh * S_ * 128;
  const u16* Kp = K2  + (size_t)bh * S_ * 128;
  const u16* Vp = VT2 + (size_t)bh * 64 * S_;
  const int qrow0 = qb * 128 + w * 16;        // group 0
  const int qrow1 = qrow0 + 64;               // group 1

  // Q fragments for both groups
  f16x8 qh[2][2], ql[2][2];
#pragma unroll
  for (int g = 0; g < 2; ++g) {
    const int qr = qrow0 + g * 64;
#pragma unroll
    for (int t = 0; t < 2; ++t) {
      qh[g][t] = *(const f16x8*)&Qp[(size_t)(qr + r16) * 128 + t * 32 + 8 * g4];
      ql[g][t] = *(const f16x8*)&Qp[(size_t)(qr + r16) * 128 + 64 + t * 32 + 8 * g4];
    }
  }

  float mrow[2][4], lrow[2][4];
  f32x4 om[2][4], ox[2][4];
#pragma unroll
  for (int g = 0; g < 2; ++g)
#pragma unroll
    for (int i = 0; i < 4; ++i) { mrow[g][i] = -1e30f; lrow[g][i] = 0.f; }
#pragma unroll
  for (int g = 0; g < 2; ++g)
#pragma unroll
    for (int db = 0; db < 4; ++db) { om[g][db] = fzero4(); ox[g][db] = fzero4(); }

  // stage one 64-key step (K: 16KB, V: 16KB) into buffer `buf`
  auto STAGE = [&](int buf, int k0) {
#pragma unroll
    for (int c4 = 0; c4 < 4; ++c4) {
      const int li = c4 * 4 + w;                     // 1KB chunk id, wave-uniform
      {// K chunk: 4 key-rows of 256B each
        const int row = li * 4 + (lane >> 4);
        const int so  = ((lane & 15) ^ (row & 7)) * 8;
        gload_lds16(Kp + (size_t)(k0 + row) * 128 + so,
                    (char*)&Kl[buf][0] + li * 1024);
      }
      {// V chunk: 8 d-rows of 128B each (plane = li>>3)
        const int plane = li >> 3;
        const int d     = (li & 7) * 8 + (lane >> 3);
        const int so    = ((lane & 7) ^ (d & 7)) * 8;
        gload_lds16(Vp + (size_t)plane * PLV + (size_t)d * S_ + k0 + so,
                    (char*)&Vl[buf][0] + li * 1024);
      }
    }
  };

  STAGE(0, 0);
  __syncthreads();

  for (int kt = 0; kt < nkt; ++kt) {
    const int buf = kt & 1;
    const int k0  = kt * 64;
    if (kt + 1 < nkt) STAGE(buf ^ 1, k0 + 64);

    // ---- QK^T: K-frags loaded once, feed both q-groups ----
    f32x4 sm[2][4], sx[2][4];
#pragma unroll
    for (int g = 0; g < 2; ++g)
#pragma unroll
      for (int ks = 0; ks < 4; ++ks) { sm[g][ks] = fzero4(); sx[g][ks] = fzero4(); }
#pragma unroll
    for (int ks = 0; ks < 4; ++ks) {
      const int row = ks * 16 + r16;
#pragma unroll
      for (int t = 0; t < 2; ++t) {
        const int sw = ((t * 4 + g4) ^ (r16 & 7)) * 8;
        f16x8 kh = *(const f16x8*)&Kl[buf][row * 128 + sw];
        f16x8 kl = *(const f16x8*)&Kl[buf][row * 128 + 64 + sw];
#pragma unroll
        for (int g = 0; g < 2; ++g) {
          sm[g][ks] = MFMA16(qh[g][t], kh, sm[g][ks]);
          sx[g][ks] = MFMA16(qh[g][t], kl, sx[g][ks]);
          sx[g][ks] = MFMA16(ql[g][t], kh, sx[g][ks]);
        }
      }
    }

    // ---- per-group: softmax -> P -> PV (Pl reused sequentially) ----
#pragma unroll
    for (int g = 0; g < 2; ++g) {
      const int qw0 = qrow0 + g * 64;
      if (g == 0 && k0 > qrow0 + 15) continue;   // group 0 fully masked this step

      float pv[4][4], corr[4];
#pragma unroll
      for (int i = 0; i < 4; ++i) {
        const int qg = qw0 + 4 * g4 + i;
        float s[4];
        float mx = -1e30f;
#pragma unroll
        for (int ks = 0; ks < 4; ++ks) {
          float v = (sm[g][ks][i] + sx[g][ks][i] * 0.015625f) * 0.125f;
          if (k0 + ks * 16 + r16 > qg) v = -1e30f;
          s[ks] = v;
          mx = fmaxf(mx, v);
        }
        mx = fmaxf(mx, __shfl_xor(mx, 1));
        mx = fmaxf(mx, __shfl_xor(mx, 2));
        mx = fmaxf(mx, __shfl_xor(mx, 4));
        mx = fmaxf(mx, __shfl_xor(mx, 8));
        float mn = fmaxf(mrow[g][i], mx);
        float cr = __expf(mrow[g][i] - mn);
        float rs = 0.f;
#pragma unroll
        for (int ks = 0; ks < 4; ++ks) {
          float e = __expf(s[ks] - mn);
          pv[ks][i] = e;
          rs += e;
        }
        rs += __shfl_xor(rs, 1);
        rs += __shfl_xor(rs, 2);
        rs += __shfl_xor(rs, 4);
        rs += __shfl_xor(rs, 8);
        lrow[g][i] = lrow[g][i] * cr + rs;
        mrow[g][i] = mn;
        corr[i] = cr;
      }
#pragma unroll
      for (int db = 0; db < 4; ++db)
#pragma unroll
        for (int i = 0; i < 4; ++i) { om[g][db][i] *= corr[i]; ox[g][db][i] *= corr[i]; }

      // P transpose via per-wave swizzled LDS (hi + lo*64 planes)
#pragma unroll
      for (int ks = 0; ks < 4; ++ks) {
        const int sl = ks * 2 + (r16 >> 3);
#pragma unroll
        for (int i = 0; i < 4; ++i) {
          const int pr = 4 * g4 + i;
          const int ad = pr * 64 + ((sl ^ (pr & 7)) * 8) + (r16 & 7);
          float p = pv[ks][i];
          _Float16 h = (_Float16)p; float hf = (float)h;
          Pl[w][ad]        = hbits(h);
          Pl[w][1024 + ad] = f2h((p - hf) * 64.0f);
        }
      }
      asm volatile("s_waitcnt lgkmcnt(0)" ::: "memory");
      __builtin_amdgcn_sched_barrier(0);

      // PV: ctx[g] += P * V
#pragma unroll
      for (int kk = 0; kk < 2; ++kk) {
        const int psw = ((kk * 4 + g4) ^ (r16 & 7)) * 8;
        f16x8 ph  = *(const f16x8*)&Pl[w][r16 * 64 + psw];
        f16x8 pl2 = *(const f16x8*)&Pl[w][1024 + r16 * 64 + psw];
#pragma unroll
        for (int db = 0; db < 4; ++db) {
          const int d = db * 16 + r16;
          const int vsw = ((kk * 4 + g4) ^ (r16 & 7)) * 8;
          f16x8 vh  = *(const f16x8*)&Vl[buf][d * 64 + vsw];
          f16x8 vl2 = *(const f16x8*)&Vl[buf][4096 + d * 64 + vsw];
          om[g][db] = MFMA16(ph, vh, om[g][db]);
          ox[g][db] = MFMA16(ph, vl2, ox[g][db]);
          ox[g][db] = MFMA16(pl2, vh, ox[g][db]);
        }
      }
      asm volatile("s_waitcnt lgkmcnt(0)" ::: "memory");
      __builtin_amdgcn_sched_barrier(0);
    }
    __syncthreads();
  }

  // ---- epilogue: ctx -> 3-plane A-side split layout (rows 4096 x 3072) ----
  const int b = bh >> 4, h = bh & 15;
#pragma unroll
  for (int g = 0; g < 2; ++g) {
#pragma unroll
    for (int db = 0; db < 4; ++db) {
#pragma unroll
      for (int i = 0; i < 4; ++i) {
        const int srow = qrow0 + g * 64 + 4 * g4 + i;
        float val = (om[g][db][i] + ox[g][db][i] * 0.015625f) / lrow[g][i];
        size_t rb = ((size_t)(b * S_ + srow)) * 3072 + h * 64 + db * 16 + r16;
        storeA3(ctx3 + rb, 1024, val);
      }
    }
  }
}

// ================= LayerNorms =================
__device__ __forceinline__ float block_sum256(float v, float* red) {
#pragma unroll
  for (int off = 32; off > 0; off >>= 1) v += __shfl_down(v, off);
  const int wid = threadIdx.x >> 6;
  if ((threadIdx.x & 63) == 0) red[wid] = v;
  __syncthreads();
  float tot = red[0] + red[1] + red[2] + red[3];
  __syncthreads();
  return tot;
}

__global__ __launch_bounds__(256) void k_ln1(const float* __restrict__ x, const float* __restrict__ ao,
                                             const float* __restrict__ w, const float* __restrict__ bb,
                                             float* __restrict__ x1f, u16* __restrict__ x1h) {
  const int row = blockIdx.x, t = threadIdx.x;
  __shared__ float red[4];
  f32x4 xv = ((const f32x4*)(x  + (size_t)row * 1024))[t];
  f32x4 av = ((const f32x4*)(ao + (size_t)row * 1024))[t];
  f32x4 v  = xv + av;
  float tot = block_sum256(v[0] + v[1] + v[2] + v[3], red);
  float mu = tot * (1.0f / 1024.0f);
  f32x4 d = v - mu;
  float totq = block_sum256(d[0]*d[0] + d[1]*d[1] + d[2]*d[2] + d[3]*d[3], red);
  float rs = rsqrtf(totq * (1.0f / 1024.0f) + 1e-5f);
  f32x4 wv = ((const f32x4*)w)[t];
  f32x4 bv = ((const f32x4*)bb)[t];
  f32x4 o;
#pragma unroll
  for (int j = 0; j < 4; ++j) o[j] = d[j] * rs * wv[j] + bv[j];
  ((f32x4*)(x1f + (size_t)row * 1024))[t] = o;
#pragma unroll
  for (int j = 0; j < 4; ++j) x1h[(size_t)row * 1024 + t * 4 + j] = f2h(o[j]);
}

__global__ __launch_bounds__(256) void k_ln2(const float* __restrict__ x1f, const float* __restrict__ pair,
                                             const float* __restrict__ w, const float* __restrict__ bb,
                                             float* __restrict__ out) {
  const int row = blockIdx.x, t = threadIdx.x;
  __shared__ float red[4];
  f32x4 v  = ((const f32x4*)(x1f + (size_t)row * 1024))[t];
  f32x4 pa = ((const f32x4*)(pair + ((size_t)row * 2)     * 1024))[t];
  f32x4 pb = ((const f32x4*)(pair + ((size_t)row * 2 + 1) * 1024))[t];
  v = v + pa + pb;
  float tot = block_sum256(v[0] + v[1] + v[2] + v[3], red);
  float mu = tot * (1.0f / 1024.0f);
  f32x4 d = v - mu;
  float totq = block_sum256(d[0]*d[0] + d[1]*d[1] + d[2]*d[2] + d[3]*d[3], red);
  float rs = rsqrtf(totq * (1.0f / 1024.0f) + 1e-5f);
  f32x4 wv = ((const f32x4*)w)[t];
  f32x4 bv = ((const f32x4*)bb)[t];
  f32x4 o;
#pragma unroll
  for (int j = 0; j < 4; ++j) o[j] = d[j] * rs * wv[j] + bv[j];
  ((f32x4*)out)[(size_t)row * 256 + t] = o;
}

// ================= gate softmax + top2 + bucket build =================
__global__ __launch_bounds__(64) void k_zero(int* p, int n) {
  int i = threadIdx.x;
  if (i < n) p[i] = 0;
}

__global__ __launch_bounds__(64) void k_gate(const float* __restrict__ x1f,
                                             const float* __restrict__ gw, const float* __restrict__ gb,
                                             float* __restrict__ topw, int* __restrict__ cnt, int* __restrict__ lists) {
  const int t = blockIdx.x, lane = threadIdx.x;
  const f32x4* xr = (const f32x4*)(x1f + (size_t)t * 1024);
  f32x4 xv[4];
#pragma unroll
  for (int c = 0; c < 4; ++c) xv[c] = xr[lane * 4 + c];
  float logit[8];
#pragma unroll
  for (int e = 0; e < 8; ++e) {
    const f32x4* wr = (const f32x4*)(gw + (size_t)e * 1024);
    float a = 0.f;
#pragma unroll
    for (int c = 0; c < 4; ++c) {
      f32x4 wv = wr[lane * 4 + c];
      a += xv[c][0]*wv[0] + xv[c][1]*wv[1] + xv[c][2]*wv[2] + xv[c][3]*wv[3];
    }
#pragma unroll
    for (int off = 32; off > 0; off >>= 1) a += __shfl_xor(a, off);
    logit[e] = a + gb[e];
  }
  if (lane == 0) {
    float mx = logit[0];
#pragma unroll
    for (int e = 1; e < 8; ++e) mx = fmaxf(mx, logit[e]);
    float g[8], se = 0.f;
#pragma unroll
    for (int e = 0; e < 8; ++e) { g[e] = __expf(logit[e] - mx); se += g[e]; }
    float inv = 1.0f / se;
#pragma unroll
    for (int e = 0; e < 8; ++e) g[e] *= inv;
    int e1 = 0;
#pragma unroll
    for (int e = 1; e < 8; ++e) if (g[e] > g[e1]) e1 = e;
    int e2 = (e1 == 0) ? 1 : 0;
#pragma unroll
    for (int e = 0; e < 8; ++e) if (e != e1 && g[e] > g[e2]) e2 = e;
    topw[t * 2]     = g[e1];
    topw[t * 2 + 1] = g[e2];
    int p1 = atomicAdd(&cnt[e1], 1); lists[e1 * 4096 + p1] = t * 2;
    int p2 = atomicAdd(&cnt[e2], 1); lists[e2 * 4096 + p2] = t * 2 + 1;
  }
}

// ================= host launch =================
extern "C" void kernel_launch(void* const* d_in, const int* in_sizes, int n_in,
                              void* d_out, int out_size, void* d_ws, size_t ws_size,
                              hipStream_t stream) {
  const float* x    = (const float*)d_in[0];
  const float* ipw  = (const float*)d_in[1];
  const float* ipb  = (const float*)d_in[2];
  const float* opw  = (const float*)d_in[3];
  const float* opb  = (const float*)d_in[4];
  const float* gw   = (const float*)d_in[5];
  const float* gb   = (const float*)d_in[6];
  const float* ew   = (const float*)d_in[7];
  const float* eb   = (const float*)d_in[8];
  const float* ln1w = (const float*)d_in[9];
  const float* ln1b = (const float*)d_in[10];
  const float* ln2w = (const float*)d_in[11];
  const float* ln2b = (const float*)d_in[12];
  char* ws = (char*)d_ws;

  // workspace layout (lifetime-aliased)
  constexpr size_t OF_WQKV = 0;                               // 3072x3072 u16
  constexpr size_t OF_WOUT = OF_WQKV + (size_t)3072*3072*2;   // 1024x3072 u16
  constexpr size_t OF_WEXP = OF_WOUT + (size_t)1024*3072*2;   // 8x1024x1024 u16
  constexpr size_t OF_RA   = OF_WEXP + (size_t)8*1024*1024*2; // rope3 -> ctx3 (4096x3072 u16)
  constexpr size_t OF_RB   = OF_RA + (size_t)4096*3072*2;     // x3 -> attn_out(f32) + x1h
  constexpr size_t OF_RC   = OF_RB + (size_t)4096*3072*2;     // q2 -> x1f
  constexpr size_t OF_RD   = OF_RC + (size_t)16777216;        // k2 -> pair (lower half)
  constexpr size_t OF_RE   = OF_RD + (size_t)16777216;        // vt2 -> pair (upper half)
  constexpr size_t OF_TOPW = OF_RE + (size_t)16777216;
  constexpr size_t OF_CNT  = OF_TOPW + 32768;
  constexpr size_t OF_LIST = OF_CNT + 256;

  u16*   Wqkv3 = (u16*)(ws + OF_WQKV);
  u16*   Wout3 = (u16*)(ws + OF_WOUT);
  u16*   WexpH = (u16*)(ws + OF_WEXP);
  u16*   rope3 = (u16*)(ws + OF_RA);
  u16*   ctx3  = (u16*)(ws + OF_RA);
  u16*   x3    = (u16*)(ws + OF_RB);
  float* attn  = (float*)(ws + OF_RB);
  u16*   x1h   = (u16*)(ws + OF_RB + (size_t)16777216);
  u16*   q2    = (u16*)(ws + OF_RC);
  float* x1f   = (float*)(ws + OF_RC);
  u16*   k2    = (u16*)(ws + OF_RD);
  u16*   vt2   = (u16*)(ws + OF_RE);
  float* pair  = (float*)(ws + OF_RD);   // 33.5 MB spans RD+RE
  float* topw  = (float*)(ws + OF_TOPW);
  int*   cnt   = (int*)(ws + OF_CNT);
  int*   lists = (int*)(ws + OF_LIST);

  (void)in_sizes; (void)n_in; (void)out_size; (void)ws_size;

  // weight conversions (every call: inputs are re-restored by harness)
  k_splitW<<<dim3((3072*1024)/256), 256, 0, stream>>>(ipw, Wqkv3, 3072*1024);
  k_splitW<<<dim3((1024*1024)/256), 256, 0, stream>>>(opw, Wout3, 1024*1024);
  k_convH <<<dim3((8*1024*1024)/256), 256, 0, stream>>>(ew, WexpH, 8*1024*1024);
  k_rope3 <<<dim3(2097152/256), 256, 0, stream>>>(x, rope3, x3);

  // fused QKV projection (split-fp16, K'=3072), 768 blocks
  gemm_qkv<<<dim3(24, 32), 256, 0, stream>>>(rope3, x3, Wqkv3, ipb, q2, k2, vt2);

  // attention (4 waves/block, QBLK=128, 512 blocks, balanced XCD decode)
  k_attn8<<<dim3(512), 256, 0, stream>>>(q2, k2, vt2, ctx3);

  // out projection (BN=64 -> 512 blocks)
  gemm_bt<2,false,64><<<dim3(16,32), 256, 0, stream>>>(ctx3, Wout3, opb, attn, M_, 1024, 3072, nullptr, nullptr, nullptr);

  // LN1 (+ fp16 copy of x1 for experts)
  k_ln1<<<dim3(M_), 256, 0, stream>>>(x, attn, ln1w, ln1b, x1f, x1h);

  // gate softmax + top2 + expert buckets
  k_zero<<<1, 64, 0, stream>>>(cnt, 8);
  k_gate<<<dim3(M_), 64, 0, stream>>>(x1f, gw, gb, topw, cnt, lists);

  // gathered top-2 expert GEMM -> weighted pair rows (BN=64)
  gemm_bt<3,true,64><<<dim3(16,32,8), 256, 0, stream>>>(x1h, WexpH, eb, pair, M_, 1024, 1024, lists, cnt, topw);

  // combine + LN2 -> output
  k_ln2<<<dim3(M_), 256, 0, stream>>>(x1f, pair, ln2w, ln2b, (float*)d_out);
}

// Round 11
// 649.853 us; speedup vs baseline: 1.0846x; 1.0846x over previous
//
#include <hip/hip_runtime.h>
#include <hip/hip_bf16.h>
#include <stdint.h>

// Problem constants
#define B_  2
#define S_  2048
#define E_  1024
#define H_  16
#define D_  64
#define NE_ 8
#define M_  4096   // B*S

typedef unsigned short u16;
typedef _Float16 f16x8 __attribute__((ext_vector_type(8)));
typedef float f32x4 __attribute__((ext_vector_type(4)));

__device__ __forceinline__ f32x4 fzero4() { f32x4 v; v[0]=0.f; v[1]=0.f; v[2]=0.f; v[3]=0.f; return v; }

__device__ __forceinline__ u16 hbits(_Float16 h) { union { _Float16 f; u16 u; } c; c.f = h; return c.u; }
__device__ __forceinline__ u16 f2h(float v) { return hbits((_Float16)v); }

// ---- fp16 3-term split storage helpers ----
// A-side planes: [Ah, Ah/64, Al*64]   W-side planes: [Wh, Wl*64, Wh/64]
// sum over stacked K' gives Ah*Wh + Ah*Wl + Al*Wh  (lo*lo dropped, ~2^-22 rel)
__device__ __forceinline__ void storeA3(u16* p, size_t stride, float v) {
  _Float16 h = (_Float16)v; float hf = (float)h;
  p[0]        = hbits(h);
  p[stride]   = f2h(hf * 0.015625f);
  p[2*stride] = f2h((v - hf) * 64.0f);
}
__device__ __forceinline__ void storeW3(u16* p, size_t stride, float v) {
  _Float16 h = (_Float16)v; float hf = (float)h;
  p[0]        = hbits(h);
  p[stride]   = f2h((v - hf) * 64.0f);
  p[2*stride] = f2h(hf * 0.015625f);
}
// attention-side 2-plane split: [Xh, Xl*64] (kernel composes terms itself)
__device__ __forceinline__ void store2s(u16* p, size_t stride, float v) {
  _Float16 h = (_Float16)v; float hf = (float)h;
  p[0]      = hbits(h);
  p[stride] = f2h((v - hf) * 64.0f);
}

__device__ __forceinline__ void gload_lds16(const void* g, void* l) {
  __builtin_amdgcn_global_load_lds(
      (const __attribute__((address_space(1))) void*)g,
      (__attribute__((address_space(3))) void*)l, 16, 0, 0);
}

#define MFMA16(a, b, c) __builtin_amdgcn_mfma_f32_16x16x32_f16((a), (b), (c), 0, 0, 0)

// ================= weight conversion =================
__global__ __launch_bounds__(256) void k_splitW(const float* __restrict__ in, u16* __restrict__ out, int total) {
  int idx = blockIdx.x * 256 + threadIdx.x;
  if (idx >= total) return;
  int n = idx >> 10, k = idx & 1023;          // K = 1024
  storeW3(out + (size_t)n * 3072 + k, 1024, in[idx]);
}

__global__ __launch_bounds__(256) void k_convH(const float* __restrict__ in, u16* __restrict__ out, int total) {
  int idx = blockIdx.x * 256 + threadIdx.x;
  if (idx < total) out[idx] = f2h(in[idx]);
}

// ================= RoPE + A-side splits =================
__global__ __launch_bounds__(256) void k_rope3(const float* __restrict__ x, u16* __restrict__ ropeA, u16* __restrict__ xA) {
  int p = blockIdx.x * 256 + threadIdx.x;     // B*S*H*32 = 2097152 pairs
  if (p >= B_ * S_ * H_ * 32) return;
  int i   = p & 31;
  int h   = (p >> 5) & 15;
  int row = p >> 9;                            // b*S + s
  int s   = row & (S_ - 1);
  int col = h * 64 + 2 * i;
  size_t base = (size_t)row * E_ + col;
  float x1 = x[base], x2 = x[base + 1];
  float inv = exp2f(-(float)i * 0.41524101186092029f);  // 10000^(-i/32)
  float ang = (float)s * inv;
  float sn, cs; sincosf(ang, &sn, &cs);
  float r1 = x1 * cs - x2 * sn;
  float r2 = x1 * sn + x2 * cs;
  size_t ob = (size_t)row * 3072 + col;
  storeA3(ropeA + ob,     1024, r1);
  storeA3(ropeA + ob + 1, 1024, r2);
  storeA3(xA + ob,        1024, x1);
  storeA3(xA + ob + 1,    1024, x2);
}

// ================= fused QKV GEMM =================
// grid (24, 32): nt 0..15 -> Q/K from rope3; nt 16..23 -> V from x3.
// C = A(4096x3072) * W(row nt*128..)^T + bias, split-fp16 3-term.
__global__ __launch_bounds__(256) void gemm_qkv(
    const u16* __restrict__ ropeA, const u16* __restrict__ xA,
    const u16* __restrict__ Wall, const float* __restrict__ ipb,
    u16* __restrict__ q2, u16* __restrict__ k2, u16* __restrict__ vt2)
{
  __shared__ __align__(16) u16 lA[128 * 32];
  __shared__ __align__(16) u16 lB[128 * 32];
  const int tid  = threadIdx.x;
  const int lane = tid & 63;
  const int wid  = tid >> 6;
  const int nt = blockIdx.x, mt = blockIdx.y;
  const u16* A = (nt < 16) ? ropeA : xA;
  long aoff[2], boff[2];
#pragma unroll
  for (int i = 0; i < 2; ++i) {
    aoff[i] = (long)(mt * 128 + i * 64 + (tid >> 2)) * 3072 + (tid & 3) * 8;
    boff[i] = (long)(nt * 128 + i * 64 + (tid >> 2)) * 3072 + (tid & 3) * 8;
  }
  f32x4 acc[4][4];
#pragma unroll
  for (int a = 0; a < 4; ++a)
#pragma unroll
    for (int b = 0; b < 4; ++b) acc[a][b] = fzero4();
  const int wm = wid >> 1, wn = wid & 1;
  const int r16 = lane & 15, g4 = lane >> 4;

  for (int k0 = 0; k0 < 3072; k0 += 32) {
#pragma unroll
    for (int i = 0; i < 2; ++i) {
      gload_lds16(A    + aoff[i] + k0, (char*)lA + i * 4096 + wid * 1024);
      gload_lds16(Wall + boff[i] + k0, (char*)lB + i * 4096 + wid * 1024);
    }
    __syncthreads();
    f16x8 af[4], bf[4];
#pragma unroll
    for (int f = 0; f < 4; ++f) {
      af[f] = *(const f16x8*)&lA[(wm * 64 + f * 16 + r16) * 32 + 8 * g4];
      bf[f] = *(const f16x8*)&lB[(wn * 64 + f * 16 + r16) * 32 + 8 * g4];
    }
#pragma unroll
    for (int fm = 0; fm < 4; ++fm)
#pragma unroll
      for (int fn = 0; fn < 4; ++fn)
        acc[fm][fn] = MFMA16(af[fm], bf[fn], acc[fm][fn]);
    __syncthreads();
  }

  const int m0 = mt * 128 + wm * 64;
  const int n0 = nt * 128 + wn * 64;
  const size_t PLV = (size_t)B_ * H_ * 64 * S_;
#pragma unroll
  for (int fm = 0; fm < 4; ++fm) {
#pragma unroll
    for (int fn = 0; fn < 4; ++fn) {
      const int colg = n0 + fn * 16 + r16;
      const float bv = ipb[colg];
#pragma unroll
      for (int i = 0; i < 4; ++i) {
        const int rowg = m0 + fm * 16 + 4 * g4 + i;
        float v = acc[fm][fn][i] + bv;
        int bb = rowg >> 11, s = rowg & 2047;
        if (nt < 16) {
          int col = colg & 1023, hh = col >> 6, d = col & 63;
          u16* tgt = (colg < 1024) ? q2 : k2;
          store2s(tgt + (((size_t)(bb * H_ + hh)) * S_ + s) * 128 + d, 64, v);
        } else {
          int col = colg - 2048, hh = col >> 6, d = col & 63;
          store2s(vt2 + (((size_t)(bb * H_ + hh)) * 64 + d) * (size_t)S_ + s, PLV, v);
        }
      }
    }
  }
}

// ================= generic GEMM (out-proj / MoE), BN-tiled =================
// EPI 2: fp32 plain write   EPI 3: MoE pair write (gathered rows)
template <int EPI, bool GATHER, int BN>
__global__ __launch_bounds__(256) void gemm_bt(
    const u16* __restrict__ A, const u16* __restrict__ Bw,
    const float* __restrict__ bias, void* __restrict__ Cout,
    int M, int N, int K,
    const int* __restrict__ lists, const int* __restrict__ cnt,
    const float* __restrict__ topw)
{
  constexpr int BCH = BN / 64;       // B-staging gloads per lane
  constexpr int FN  = BN / 32;       // N-fragments per wave
  __shared__ __align__(16) u16 lA[128 * 32];
  __shared__ __align__(16) u16 lB[BN * 32];
  const int tid  = threadIdx.x;
  const int lane = tid & 63;
  const int wid  = tid >> 6;
  const int nt = blockIdx.x, mt = blockIdx.y;
  int cnt_e = 0;
  const int* listE = nullptr;
  if constexpr (GATHER) {
    int e = blockIdx.z;
    cnt_e = cnt[e];
    if (mt * 128 >= cnt_e) return;
    Bw   += (size_t)e * N * K;
    bias += (size_t)e * N;
    listE = lists + e * 4096;
  }
  long aoff[2], boff[BCH];
#pragma unroll
  for (int i = 0; i < 2; ++i) {
    long arow;
    if constexpr (GATHER) {
      int li = mt * 128 + i * 64 + (tid >> 2);
      int entry = (li < cnt_e) ? listE[li] : 0;
      arow = entry >> 1;
    } else {
      arow = mt * 128 + i * 64 + (tid >> 2);
    }
    aoff[i] = arow * (long)K + (tid & 3) * 8;
  }
#pragma unroll
  for (int i = 0; i < BCH; ++i)
    boff[i] = (long)(nt * BN + i * 64 + (tid >> 2)) * K + (tid & 3) * 8;

  f32x4 acc[4][FN];
#pragma unroll
  for (int a = 0; a < 4; ++a)
#pragma unroll
    for (int b = 0; b < FN; ++b) acc[a][b] = fzero4();
  const int wm = wid >> 1, wn = wid & 1;
  const int r16 = lane & 15, g4 = lane >> 4;

  for (int k0 = 0; k0 < K; k0 += 32) {
#pragma unroll
    for (int i = 0; i < 2; ++i)
      gload_lds16(A + aoff[i] + k0, (char*)lA + i * 4096 + wid * 1024);
#pragma unroll
    for (int i = 0; i < BCH; ++i)
      gload_lds16(Bw + boff[i] + k0, (char*)lB + i * 4096 + wid * 1024);
    __syncthreads();
    f16x8 af[4], bf[FN];
#pragma unroll
    for (int f = 0; f < 4; ++f)
      af[f] = *(const f16x8*)&lA[(wm * 64 + f * 16 + r16) * 32 + 8 * g4];
#pragma unroll
    for (int f = 0; f < FN; ++f)
      bf[f] = *(const f16x8*)&lB[(wn * (FN * 16) + f * 16 + r16) * 32 + 8 * g4];
#pragma unroll
    for (int fm = 0; fm < 4; ++fm)
#pragma unroll
      for (int fn = 0; fn < FN; ++fn)
        acc[fm][fn] = MFMA16(af[fm], bf[fn], acc[fm][fn]);
    __syncthreads();
  }

  const int m0 = mt * 128 + wm * 64;
  const int n0 = nt * BN + wn * (FN * 16);
#pragma unroll
  for (int fm = 0; fm < 4; ++fm) {
#pragma unroll
    for (int fn = 0; fn < FN; ++fn) {
      const int colg = n0 + fn * 16 + r16;
      const float bv = bias[colg];
#pragma unroll
      for (int i = 0; i < 4; ++i) {
        const int rowg = m0 + fm * 16 + 4 * g4 + i;
        float v = acc[fm][fn][i] + bv;
        if constexpr (EPI == 2) {
          ((float*)Cout)[(size_t)rowg * N + colg] = v;
        } else {
          if (rowg < cnt_e) {
            int entry = listE[rowg];
            ((float*)Cout)[(size_t)entry * 1024 + colg] = v * topw[entry];
          }
        }
      }
    }
  }
}

// ================= flash attention v6: 8 waves/block, QBLK=128, KVBLK=64 =================
// Round-8-verified PER-WAVE code (16 q-rows/wave, 64-key steps, same swizzles).
// 8 waves share the K/V tiles -> 2 waves/SIMD guaranteed (vs 1 at 4-wave blocks),
// staging per wave halves. LDS = 32K + 32V + 32P = 96KB -> 1 block/CU.
__global__ __launch_bounds__(512) void k_attnW8(const u16* __restrict__ Q2, const u16* __restrict__ K2,
                                                const u16* __restrict__ VT2, u16* __restrict__ ctx3) {
  __shared__ __align__(16) u16 Kl[2][64 * 128];       // 32 KB  [buf][key][hi64|lo64]
  __shared__ __align__(16) u16 Vl[2][2 * 64 * 64];    // 32 KB  [buf][plane][d][k]
  __shared__ __align__(16) u16 Pl[8][2 * 1024];       // 32 KB  [wave][plane][16 x 64]
  const int tid  = threadIdx.x;
  const int w    = tid >> 6;                          // [0,8)
  const int lane = tid & 63;
  const int r16 = lane & 15, g4 = lane >> 4;

  // Balanced XCD decode for 512 blocks (qb in [0,16)): CU x gets slots {x, x+32}
  // with complementary nkt -> every CU totals 34 K-steps.
  const int bid  = blockIdx.x;
  const int xcd  = bid & 7;
  const int slot = bid >> 3;          // [0,64)
  const int rnd  = slot >> 4;         // [0,4)
  const int c    = slot & 15;
  const int bh   = xcd + 8 * rnd;
  const int qb   = (rnd == 0 || rnd == 3) ? (15 - c) : c;   // [0,16)
  const int nkt  = 2 * qb + 2;        // 64-key steps

  const size_t PLV = (size_t)B_ * H_ * 64 * S_;
  const u16* Qp = Q2  + (size_t)bh * S_ * 128;
  const u16* Kp = K2  + (size_t)bh * S_ * 128;
  const u16* Vp = VT2 + (size_t)bh * 64 * S_;
  const int qw0 = qb * 128 + w * 16;

  // Q fragments (held in regs for the whole kernel)
  f16x8 qh[2], ql[2];
#pragma unroll
  for (int t = 0; t < 2; ++t) {
    qh[t] = *(const f16x8*)&Qp[(size_t)(qw0 + r16) * 128 + t * 32 + 8 * g4];
    ql[t] = *(const f16x8*)&Qp[(size_t)(qw0 + r16) * 128 + 64 + t * 32 + 8 * g4];
  }

  float mrow[4], lrow[4];
  f32x4 om[4], ox[4];
#pragma unroll
  for (int i = 0; i < 4; ++i) { mrow[i] = -1e30f; lrow[i] = 0.f; }
#pragma unroll
  for (int db = 0; db < 4; ++db) { om[db] = fzero4(); ox[db] = fzero4(); }

  // stage one 64-key step (K: 16KB = chunks 0..15, V: 16KB = chunks 16..31);
  // 8 waves x 4 chunks of 1KB.
  auto STAGE = [&](int buf, int k0) {
#pragma unroll
    for (int c4 = 0; c4 < 4; ++c4) {
      const int li = c4 * 8 + w;                     // 1KB chunk id, wave-uniform
      if (li < 16) {                                 // K chunk: 4 key-rows of 256B
        const int row = li * 4 + (lane >> 4);        // key within tile [0,64)
        const int so  = ((lane & 15) ^ (row & 7)) * 8;
        gload_lds16(Kp + (size_t)(k0 + row) * 128 + so,
                    (char*)&Kl[buf][0] + li * 1024);
      } else {                                       // V chunk: 8 d-rows of 128B
        const int lv    = li - 16;                   // [0,16)
        const int plane = lv >> 3;
        const int d     = (lv & 7) * 8 + (lane >> 3);
        const int so    = ((lane & 7) ^ (d & 7)) * 8;
        gload_lds16(Vp + (size_t)plane * PLV + (size_t)d * S_ + k0 + so,
                    (char*)&Vl[buf][0] + lv * 1024);
      }
    }
  };

  STAGE(0, 0);
  __syncthreads();

  for (int kt = 0; kt < nkt; ++kt) {
    const int buf = kt & 1;
    const int k0  = kt * 64;
    if (kt + 1 < nkt) STAGE(buf ^ 1, k0 + 64);

    if (k0 <= qw0 + 15) {   // wave not fully masked this step
      // ---- QK^T over 4 key-subtiles of 16 ----
      f32x4 sm[4], sx[4];
#pragma unroll
      for (int ks = 0; ks < 4; ++ks) { sm[ks] = fzero4(); sx[ks] = fzero4(); }
#pragma unroll
      for (int ks = 0; ks < 4; ++ks) {
        const int row = ks * 16 + r16;
#pragma unroll
        for (int t = 0; t < 2; ++t) {
          const int sw = ((t * 4 + g4) ^ (r16 & 7)) * 8;
          f16x8 kh = *(const f16x8*)&Kl[buf][row * 128 + sw];
          f16x8 kl = *(const f16x8*)&Kl[buf][row * 128 + 64 + sw];
          sm[ks] = MFMA16(qh[t], kh, sm[ks]);
          sx[ks] = MFMA16(qh[t], kl, sx[ks]);
          sx[ks] = MFMA16(ql[t], kh, sx[ks]);
        }
      }

      // ---- online softmax ----
      float pv[4][4], corr[4];
#pragma unroll
      for (int i = 0; i < 4; ++i) {
        const int qg = qw0 + 4 * g4 + i;
        float s[4];
        float mx = -1e30f;
#pragma unroll
        for (int ks = 0; ks < 4; ++ks) {
          float v = (sm[ks][i] + sx[ks][i] * 0.015625f) * 0.125f;
          if (k0 + ks * 16 + r16 > qg) v = -1e30f;
          s[ks] = v;
          mx = fmaxf(mx, v);
        }
        mx = fmaxf(mx, __shfl_xor(mx, 1));
        mx = fmaxf(mx, __shfl_xor(mx, 2));
        mx = fmaxf(mx, __shfl_xor(mx, 4));
        mx = fmaxf(mx, __shfl_xor(mx, 8));
        float mn = fmaxf(mrow[i], mx);
        float cr = __expf(mrow[i] - mn);
        float rs = 0.f;
#pragma unroll
        for (int ks = 0; ks < 4; ++ks) {
          float e = __expf(s[ks] - mn);
          pv[ks][i] = e;
          rs += e;
        }
        rs += __shfl_xor(rs, 1);
        rs += __shfl_xor(rs, 2);
        rs += __shfl_xor(rs, 4);
        rs += __shfl_xor(rs, 8);
        lrow[i] = lrow[i] * cr + rs;
        mrow[i] = mn;
        corr[i] = cr;
      }
#pragma unroll
      for (int db = 0; db < 4; ++db)
#pragma unroll
        for (int i = 0; i < 4; ++i) { om[db][i] *= corr[i]; ox[db][i] *= corr[i]; }

      // ---- P transpose via per-wave swizzled LDS (hi + lo*64 planes) ----
#pragma unroll
      for (int ks = 0; ks < 4; ++ks) {
        const int sl = ks * 2 + (r16 >> 3);          // logical 8-u16 slot
#pragma unroll
        for (int i = 0; i < 4; ++i) {
          const int pr = 4 * g4 + i;
          const int ad = pr * 64 + ((sl ^ (pr & 7)) * 8) + (r16 & 7);
          float p = pv[ks][i];
          _Float16 h = (_Float16)p; float hf = (float)h;
          Pl[w][ad]        = hbits(h);
          Pl[w][1024 + ad] = f2h((p - hf) * 64.0f);
        }
      }
      asm volatile("s_waitcnt lgkmcnt(0)" ::: "memory");
      __builtin_amdgcn_sched_barrier(0);

      // ---- PV: ctx += P * V ----
#pragma unroll
      for (int kk = 0; kk < 2; ++kk) {
        const int psw = ((kk * 4 + g4) ^ (r16 & 7)) * 8;
        f16x8 ph  = *(const f16x8*)&Pl[w][r16 * 64 + psw];
        f16x8 pl2 = *(const f16x8*)&Pl[w][1024 + r16 * 64 + psw];
#pragma unroll
        for (int db = 0; db < 4; ++db) {
          const int d = db * 16 + r16;
          const int vsw = ((kk * 4 + g4) ^ (r16 & 7)) * 8;
          f16x8 vh  = *(const f16x8*)&Vl[buf][d * 64 + vsw];
          f16x8 vl2 = *(const f16x8*)&Vl[buf][4096 + d * 64 + vsw];
          om[db] = MFMA16(ph, vh, om[db]);
          ox[db] = MFMA16(ph, vl2, ox[db]);
          ox[db] = MFMA16(pl2, vh, ox[db]);
        }
      }
    }
    __syncthreads();
  }

  // ---- epilogue: ctx -> 3-plane A-side split layout (rows 4096 x 3072) ----
  const int b = bh >> 4, h = bh & 15;
#pragma unroll
  for (int db = 0; db < 4; ++db) {
#pragma unroll
    for (int i = 0; i < 4; ++i) {
      const int srow = qw0 + 4 * g4 + i;
      float val = (om[db][i] + ox[db][i] * 0.015625f) / lrow[i];
      size_t rb = ((size_t)(b * S_ + srow)) * 3072 + h * 64 + db * 16 + r16;
      storeA3(ctx3 + rb, 1024, val);
    }
  }
}

// ================= LayerNorms =================
__device__ __forceinline__ float block_sum256(float v, float* red) {
#pragma unroll
  for (int off = 32; off > 0; off >>= 1) v += __shfl_down(v, off);
  const int wid = threadIdx.x >> 6;
  if ((threadIdx.x & 63) == 0) red[wid] = v;
  __syncthreads();
  float tot = red[0] + red[1] + red[2] + red[3];
  __syncthreads();
  return tot;
}

__global__ __launch_bounds__(256) void k_ln1(const float* __restrict__ x, const float* __restrict__ ao,
                                             const float* __restrict__ w, const float* __restrict__ bb,
                                             float* __restrict__ x1f, u16* __restrict__ x1h) {
  const int row = blockIdx.x, t = threadIdx.x;
  __shared__ float red[4];
  f32x4 xv = ((const f32x4*)(x  + (size_t)row * 1024))[t];
  f32x4 av = ((const f32x4*)(ao + (size_t)row * 1024))[t];
  f32x4 v  = xv + av;
  float tot = block_sum256(v[0] + v[1] + v[2] + v[3], red);
  float mu = tot * (1.0f / 1024.0f);
  f32x4 d = v - mu;
  float totq = block_sum256(d[0]*d[0] + d[1]*d[1] + d[2]*d[2] + d[3]*d[3], red);
  float rs = rsqrtf(totq * (1.0f / 1024.0f) + 1e-5f);
  f32x4 wv = ((const f32x4*)w)[t];
  f32x4 bv = ((const f32x4*)bb)[t];
  f32x4 o;
#pragma unroll
  for (int j = 0; j < 4; ++j) o[j] = d[j] * rs * wv[j] + bv[j];
  ((f32x4*)(x1f + (size_t)row * 1024))[t] = o;
#pragma unroll
  for (int j = 0; j < 4; ++j) x1h[(size_t)row * 1024 + t * 4 + j] = f2h(o[j]);
}

__global__ __launch_bounds__(256) void k_ln2(const float* __restrict__ x1f, const float* __restrict__ pair,
                                             const float* __restrict__ w, const float* __restrict__ bb,
                                             float* __restrict__ out) {
  const int row = blockIdx.x, t = threadIdx.x;
  __shared__ float red[4];
  f32x4 v  = ((const f32x4*)(x1f + (size_t)row * 1024))[t];
  f32x4 pa = ((const f32x4*)(pair + ((size_t)row * 2)     * 1024))[t];
  f32x4 pb = ((const f32x4*)(pair + ((size_t)row * 2 + 1) * 1024))[t];
  v = v + pa + pb;
  float tot = block_sum256(v[0] + v[1] + v[2] + v[3], red);
  float mu = tot * (1.0f / 1024.0f);
  f32x4 d = v - mu;
  float totq = block_sum256(d[0]*d[0] + d[1]*d[1] + d[2]*d[2] + d[3]*d[3], red);
  float rs = rsqrtf(totq * (1.0f / 1024.0f) + 1e-5f);
  f32x4 wv = ((const f32x4*)w)[t];
  f32x4 bv = ((const f32x4*)bb)[t];
  f32x4 o;
#pragma unroll
  for (int j = 0; j < 4; ++j) o[j] = d[j] * rs * wv[j] + bv[j];
  ((f32x4*)out)[(size_t)row * 256 + t] = o;
}

// ================= gate softmax + top2 + bucket build =================
__global__ __launch_bounds__(64) void k_zero(int* p, int n) {
  int i = threadIdx.x;
  if (i < n) p[i] = 0;
}

__global__ __launch_bounds__(64) void k_gate(const float* __restrict__ x1f,
                                             const float* __restrict__ gw, const float* __restrict__ gb,
                                             float* __restrict__ topw, int* __restrict__ cnt, int* __restrict__ lists) {
  const int t = blockIdx.x, lane = threadIdx.x;
  const f32x4* xr = (const f32x4*)(x1f + (size_t)t * 1024);
  f32x4 xv[4];
#pragma unroll
  for (int c = 0; c < 4; ++c) xv[c] = xr[lane * 4 + c];
  float logit[8];
#pragma unroll
  for (int e = 0; e < 8; ++e) {
    const f32x4* wr = (const f32x4*)(gw + (size_t)e * 1024);
    float a = 0.f;
#pragma unroll
    for (int c = 0; c < 4; ++c) {
      f32x4 wv = wr[lane * 4 + c];
      a += xv[c][0]*wv[0] + xv[c][1]*wv[1] + xv[c][2]*wv[2] + xv[c][3]*wv[3];
    }
#pragma unroll
    for (int off = 32; off > 0; off >>= 1) a += __shfl_xor(a, off);
    logit[e] = a + gb[e];
  }
  if (lane == 0) {
    float mx = logit[0];
#pragma unroll
    for (int e = 1; e < 8; ++e) mx = fmaxf(mx, logit[e]);
    float g[8], se = 0.f;
#pragma unroll
    for (int e = 0; e < 8; ++e) { g[e] = __expf(logit[e] - mx); se += g[e]; }
    float inv = 1.0f / se;
#pragma unroll
    for (int e = 0; e < 8; ++e) g[e] *= inv;
    int e1 = 0;
#pragma unroll
    for (int e = 1; e < 8; ++e) if (g[e] > g[e1]) e1 = e;
    int e2 = (e1 == 0) ? 1 : 0;
#pragma unroll
    for (int e = 0; e < 8; ++e) if (e != e1 && g[e] > g[e2]) e2 = e;
    topw[t * 2]     = g[e1];
    topw[t * 2 + 1] = g[e2];
    int p1 = atomicAdd(&cnt[e1], 1); lists[e1 * 4096 + p1] = t * 2;
    int p2 = atomicAdd(&cnt[e2], 1); lists[e2 * 4096 + p2] = t * 2 + 1;
  }
}

// ================= host launch =================
extern "C" void kernel_launch(void* const* d_in, const int* in_sizes, int n_in,
                              void* d_out, int out_size, void* d_ws, size_t ws_size,
                              hipStream_t stream) {
  const float* x    = (const float*)d_in[0];
  const float* ipw  = (const float*)d_in[1];
  const float* ipb  = (const float*)d_in[2];
  const float* opw  = (const float*)d_in[3];
  const float* opb  = (const float*)d_in[4];
  const float* gw   = (const float*)d_in[5];
  const float* gb   = (const float*)d_in[6];
  const float* ew   = (const float*)d_in[7];
  const float* eb   = (const float*)d_in[8];
  const float* ln1w = (const float*)d_in[9];
  const float* ln1b = (const float*)d_in[10];
  const float* ln2w = (const float*)d_in[11];
  const float* ln2b = (const float*)d_in[12];
  char* ws = (char*)d_ws;

  // workspace layout (lifetime-aliased)
  constexpr size_t OF_WQKV = 0;                               // 3072x3072 u16
  constexpr size_t OF_WOUT = OF_WQKV + (size_t)3072*3072*2;   // 1024x3072 u16
  constexpr size_t OF_WEXP = OF_WOUT + (size_t)1024*3072*2;   // 8x1024x1024 u16
  constexpr size_t OF_RA   = OF_WEXP + (size_t)8*1024*1024*2; // rope3 -> ctx3 (4096x3072 u16)
  constexpr size_t OF_RB   = OF_RA + (size_t)4096*3072*2;     // x3 -> attn_out(f32) + x1h
  constexpr size_t OF_RC   = OF_RB + (size_t)4096*3072*2;     // q2 -> x1f
  constexpr size_t OF_RD   = OF_RC + (size_t)16777216;        // k2 -> pair (lower half)
  constexpr size_t OF_RE   = OF_RD + (size_t)16777216;        // vt2 -> pair (upper half)
  constexpr size_t OF_TOPW = OF_RE + (size_t)16777216;
  constexpr size_t OF_CNT  = OF_TOPW + 32768;
  constexpr size_t OF_LIST = OF_CNT + 256;

  u16*   Wqkv3 = (u16*)(ws + OF_WQKV);
  u16*   Wout3 = (u16*)(ws + OF_WOUT);
  u16*   WexpH = (u16*)(ws + OF_WEXP);
  u16*   rope3 = (u16*)(ws + OF_RA);
  u16*   ctx3  = (u16*)(ws + OF_RA);
  u16*   x3    = (u16*)(ws + OF_RB);
  float* attn  = (float*)(ws + OF_RB);
  u16*   x1h   = (u16*)(ws + OF_RB + (size_t)16777216);
  u16*   q2    = (u16*)(ws + OF_RC);
  float* x1f   = (float*)(ws + OF_RC);
  u16*   k2    = (u16*)(ws + OF_RD);
  u16*   vt2   = (u16*)(ws + OF_RE);
  float* pair  = (float*)(ws + OF_RD);   // 33.5 MB spans RD+RE
  float* topw  = (float*)(ws + OF_TOPW);
  int*   cnt   = (int*)(ws + OF_CNT);
  int*   lists = (int*)(ws + OF_LIST);

  (void)in_sizes; (void)n_in; (void)out_size; (void)ws_size;

  // weight conversions (every call: inputs are re-restored by harness)
  k_splitW<<<dim3((3072*1024)/256), 256, 0, stream>>>(ipw, Wqkv3, 3072*1024);
  k_splitW<<<dim3((1024*1024)/256), 256, 0, stream>>>(opw, Wout3, 1024*1024);
  k_convH <<<dim3((8*1024*1024)/256), 256, 0, stream>>>(ew, WexpH, 8*1024*1024);
  k_rope3 <<<dim3(2097152/256), 256, 0, stream>>>(x, rope3, x3);

  // fused QKV projection (split-fp16, K'=3072), 768 blocks
  gemm_qkv<<<dim3(24, 32), 256, 0, stream>>>(rope3, x3, Wqkv3, ipb, q2, k2, vt2);

  // attention (8 waves/block, QBLK=128, 512 blocks, balanced XCD decode)
  k_attnW8<<<dim3(512), 512, 0, stream>>>(q2, k2, vt2, ctx3);

  // out projection (BN=64 -> 512 blocks)
  gemm_bt<2,false,64><<<dim3(16,32), 256, 0, stream>>>(ctx3, Wout3, opb, attn, M_, 1024, 3072, nullptr, nullptr, nullptr);

  // LN1 (+ fp16 copy of x1 for experts)
  k_ln1<<<dim3(M_), 256, 0, stream>>>(x, attn, ln1w, ln1b, x1f, x1h);

  // gate softmax + top2 + expert buckets
  k_zero<<<1, 64, 0, stream>>>(cnt, 8);
  k_gate<<<dim3(M_), 64, 0, stream>>>(x1f, gw, gb, topw, cnt, lists);

  // gathered top-2 expert GEMM -> weighted pair rows (BN=64)
  gemm_bt<3,true,64><<<dim3(16,32,8), 256, 0, stream>>>(x1h, WexpH, eb, pair, M_, 1024, 1024, lists, cnt, topw);

  // combine + LN2 -> output
  k_ln2<<<dim3(M_), 256, 0, stream>>>(x1f, pair, ln2w, ln2b, (float*)d_out);
}